// Round 1
// baseline (279.152 us; speedup 1.0000x reference)
//
#include <hip/hip_runtime.h>
#include <stdint.h>

#define DEV __device__ __forceinline__

typedef float f32x4 __attribute__((ext_vector_type(4)));
typedef __bf16 bf16x8 __attribute__((ext_vector_type(8)));
typedef short short8 __attribute__((ext_vector_type(8)));
typedef short short4v __attribute__((ext_vector_type(4)));

DEV unsigned short f2bf(float f) {
    union { float f; unsigned u; } c; c.f = f;
    unsigned u = c.u;
    u += 0x7fffu + ((u >> 16) & 1u);   // round-to-nearest-even
    return (unsigned short)(u >> 16);
}

DEV void async_ld16(const void* g, void* l) {
    __builtin_amdgcn_global_load_lds(
        (const __attribute__((address_space(1))) unsigned int*)g,
        (__attribute__((address_space(3))) unsigned int*)l, 16, 0, 0);
}

DEV f32x4 mfma16(bf16x8 a, bf16x8 b, f32x4 c) {
    return __builtin_amdgcn_mfma_f32_16x16x32_bf16(a, b, c, 0, 0, 0);
}

// ---------------- prep: x fp32 -> bf16 ----------------
__global__ __launch_bounds__(256) void k_cvt_x(const float* __restrict__ x,
                                               unsigned short* __restrict__ xb) {
    int t = blockIdx.x * 256 + threadIdx.x;
    const float4* xp = (const float4*)x;
    float4 a = xp[t * 2], b = xp[t * 2 + 1];
    short8 o;
    o[0] = (short)f2bf(a.x); o[1] = (short)f2bf(a.y);
    o[2] = (short)f2bf(a.z); o[3] = (short)f2bf(a.w);
    o[4] = (short)f2bf(b.x); o[5] = (short)f2bf(b.y);
    o[6] = (short)f2bf(b.z); o[7] = (short)f2bf(b.w);
    *(short8*)(xb + t * 8) = o;
}

// ---------------- prep: W [1024][3072] fp32 -> Wt [3072][1024] bf16 ----------
__global__ __launch_bounds__(256) void k_tr_w(const float* __restrict__ W,
                                              unsigned short* __restrict__ Wt) {
    __shared__ float T[64][65];
    int n0 = blockIdx.x * 64, k0 = blockIdx.y * 64;
    int t = threadIdx.x;
    int r = t >> 4, c4 = (t & 15) * 4;
    for (int i = 0; i < 4; i++) {
        int row = r + i * 16;
        float4 v = *(const float4*)(W + (k0 + row) * 3072 + n0 + c4);
        T[row][c4] = v.x; T[row][c4 + 1] = v.y; T[row][c4 + 2] = v.z; T[row][c4 + 3] = v.w;
    }
    __syncthreads();
    for (int i = 0; i < 4; i++) {
        int nrow = r + i * 16;
        short4v o;
        o[0] = (short)f2bf(T[c4 + 0][nrow]);
        o[1] = (short)f2bf(T[c4 + 1][nrow]);
        o[2] = (short)f2bf(T[c4 + 2][nrow]);
        o[3] = (short)f2bf(T[c4 + 3][nrow]);
        *(short4v*)(Wt + (n0 + nrow) * 1024 + k0 + c4) = o;
    }
}

// ---------------- QKV GEMM: [8192x1024]x[1024x3072] + bias, scatter Q/K/Vt --
// Q stored [bh][n][d]*32, K stored [bh][n][d], V stored transposed [bh][d][n]
__global__ __launch_bounds__(256, 2) void k_qkv(const unsigned short* __restrict__ xb,
                                                const unsigned short* __restrict__ Wt,
                                                const float* __restrict__ bias,
                                                unsigned short* __restrict__ Q,
                                                unsigned short* __restrict__ K,
                                                unsigned short* __restrict__ V) {
    __shared__ __align__(16) unsigned short As[128 * 64];  // XOR-swizzled chunks (mask 7)
    __shared__ __align__(16) unsigned short Bs[128 * 64];
    const int m0 = blockIdx.y * 128, n0 = blockIdx.x * 128;
    const int wave = threadIdx.x >> 6, lane = threadIdx.x & 63;
    const int wm = (wave & 1) * 64, wn = (wave >> 1) * 64;
    f32x4 acc[4][4] = {};
    const int slr = wave * 32 + (lane >> 3);  // staging local row (+ i*8)
    const int scs = lane & 7;                 // staging chunk slot

    for (int kt = 0; kt < 16; kt++) {
        __syncthreads();
        for (int i = 0; i < 4; i++) {
            int lr = slr + i * 8;
            int c = scs ^ (lr & 7);
            async_ld16(xb + (m0 + lr) * 1024 + kt * 64 + c * 8,
                       (void*)(As + (wave * 32 + i * 8) * 64));
            async_ld16(Wt + (n0 + lr) * 1024 + kt * 64 + c * 8,
                       (void*)(Bs + (wave * 32 + i * 8) * 64));
        }
        __syncthreads();
        for (int ks = 0; ks < 2; ks++) {
            bf16x8 af[4], bfr[4];
            int c0 = ks * 4 + (lane >> 4);
            for (int tm = 0; tm < 4; tm++) {
                int row = wm + tm * 16 + (lane & 15);
                af[tm] = *(const bf16x8*)(As + row * 64 + (c0 ^ (row & 7)) * 8);
            }
            for (int tn = 0; tn < 4; tn++) {
                int row = wn + tn * 16 + (lane & 15);
                bfr[tn] = *(const bf16x8*)(Bs + row * 64 + (c0 ^ (row & 7)) * 8);
            }
            for (int tm = 0; tm < 4; tm++)
                for (int tn = 0; tn < 4; tn++)
                    acc[tm][tn] = mfma16(af[tm], bfr[tn], acc[tm][tn]);
        }
    }

    // epilogue: bias + scatter. col -> (h = c/192, d = (c%192)/3, which = c%3)
    const int batch = m0 >> 11;
    for (int tn = 0; tn < 4; tn++) {
        int col = n0 + wn + tn * 16 + (lane & 15);
        int h = col / 192;
        int rem = col - h * 192;
        int d = rem / 3;
        int which = rem - d * 3;
        float bv = bias[col];
        int bh = batch * 16 + h;
        unsigned qk_base = (unsigned)bh * 131072u + (unsigned)d;
        unsigned v_base = ((unsigned)bh * 64u + (unsigned)d) * 2048u;
        unsigned short* dst = which == 0 ? Q : (which == 1 ? K : V);
        float mult = which == 0 ? 32.0f : 1.0f;  // fold attn scale sqrt(1024)=32 into Q
        for (int tm = 0; tm < 4; tm++) {
            int rbase = m0 + wm + tm * 16 + ((lane >> 4) * 4);
            for (int r = 0; r < 4; r++) {
                int row = rbase + r;
                unsigned token = (unsigned)(row & 2047);
                float val = (acc[tm][tn][r] + bv) * mult;
                unsigned idx = (which == 2) ? (v_base + token) : (qk_base + token * 64u);
                dst[idx] = f2bf(val);
            }
        }
    }
}

// ---------------- fused attention: O = (Q*32 . K^T) . V, no softmax ---------
__global__ __launch_bounds__(256, 2) void k_attn(const unsigned short* __restrict__ Q,
                                                 const unsigned short* __restrict__ K,
                                                 const unsigned short* __restrict__ V,
                                                 float* __restrict__ out) {
    __shared__ __align__(16) unsigned short Ks[128 * 64];   // [key][d], swizzle mask 7
    __shared__ __align__(16) unsigned short Vs[64 * 128];   // [d][key], swizzle mask 15
    __shared__ __align__(16) unsigned short Ss[4][32 * 128];// per-wave S, swizzle mask 7
    const int bh = blockIdx.y;
    const int q0 = blockIdx.x * 128;
    const int wave = threadIdx.x >> 6, lane = threadIdx.x & 63;
    const unsigned base = (unsigned)bh * 131072u;
    const int wq0 = q0 + wave * 32;

    // Q fragments held in registers the whole kernel (A-operand layout)
    bf16x8 qf[2][2];
    for (int tm = 0; tm < 2; tm++)
        for (int ks = 0; ks < 2; ks++)
            qf[tm][ks] = *(const bf16x8*)(Q + base +
                          (unsigned)(wq0 + tm * 16 + (lane & 15)) * 64u +
                          ks * 32 + (lane >> 4) * 8);

    f32x4 oacc[2][4] = {};
    unsigned short* Sw = Ss[wave];
    const int klr = wave * 32 + (lane >> 3), kcs = lane & 7;
    const int vlr = wave * 16 + (lane >> 4), vcs = lane & 15;

    for (int j = 0; j < 16; j++) {
        __syncthreads();
        for (int i = 0; i < 4; i++) {  // stage K tile [128][64]
            int lr = klr + i * 8;
            int c = kcs ^ (lr & 7);
            async_ld16(K + base + (unsigned)(j * 128 + lr) * 64u + c * 8,
                       (void*)(Ks + (wave * 32 + i * 8) * 64));
        }
        for (int i = 0; i < 4; i++) {  // stage V^T tile [64][128]
            int lr = vlr + i * 4;
            int c = vcs ^ (lr & 15);
            async_ld16(V + base + (unsigned)lr * 2048u + j * 128 + c * 8,
                       (void*)(Vs + (wave * 16 + i * 4) * 128));
        }
        __syncthreads();

        // S = Q.K^T  (K-dim = d = 64, complete within this tile)
        for (int tn = 0; tn < 8; tn++) {
            bf16x8 kb[2];
            int krow = tn * 16 + (lane & 15);
            for (int ks = 0; ks < 2; ks++) {
                int c0 = ks * 4 + (lane >> 4);
                kb[ks] = *(const bf16x8*)(Ks + krow * 64 + (c0 ^ (krow & 7)) * 8);
            }
            for (int tm = 0; tm < 2; tm++) {
                f32x4 s = {};
                s = mfma16(qf[tm][0], kb[0], s);
                s = mfma16(qf[tm][1], kb[1], s);
                // C-layout -> bf16 -> per-wave LDS (row-major, chunk-XOR-swizzled)
                int col = tn * 16 + (lane & 15);
                int rb = tm * 16 + (lane >> 4) * 4;
                for (int r = 0; r < 4; r++) {
                    int row = rb + r;
                    int cch = (col >> 3) ^ (row & 7);
                    Sw[row * 128 + cch * 8 + (col & 7)] = f2bf(s[r]);
                }
            }
        }

        // O += S.V
        for (int ks2 = 0; ks2 < 4; ks2++) {
            bf16x8 aS[2], bV[4];
            int c0 = ks2 * 4 + (lane >> 4);
            for (int tm = 0; tm < 2; tm++) {
                int row = tm * 16 + (lane & 15);
                aS[tm] = *(const bf16x8*)(Sw + row * 128 + ((c0 ^ (row & 7))) * 8);
            }
            for (int tn = 0; tn < 4; tn++) {
                int vrow = tn * 16 + (lane & 15);
                bV[tn] = *(const bf16x8*)(Vs + vrow * 128 + (c0 ^ (vrow & 15)) * 8);
            }
            for (int tm = 0; tm < 2; tm++)
                for (int tn = 0; tn < 4; tn++)
                    oacc[tm][tn] = mfma16(aS[tm], bV[tn], oacc[tm][tn]);
        }
    }

    // epilogue: out [bh][n][d] fp32
    for (int tm = 0; tm < 2; tm++)
        for (int tn = 0; tn < 4; tn++) {
            int rb = wq0 + tm * 16 + (lane >> 4) * 4;
            int col = tn * 16 + (lane & 15);
            for (int r = 0; r < 4; r++)
                out[base + (unsigned)(rb + r) * 64u + col] = oacc[tm][tn][r];
        }
}

extern "C" void kernel_launch(void* const* d_in, const int* in_sizes, int n_in,
                              void* d_out, int out_size, void* d_ws, size_t ws_size,
                              hipStream_t stream) {
    const float* x = (const float*)d_in[0];
    const float* W = (const float*)d_in[1];
    const float* b = (const float*)d_in[2];
    float* out = (float*)d_out;

    unsigned short* xb = (unsigned short*)d_ws;   // 8,388,608 bf16
    unsigned short* Wt = xb + 8388608;            // 3,145,728 bf16
    unsigned short* Qb = Wt + 3145728;            // 8,388,608 bf16 (scaled by 32)
    unsigned short* Kb = Qb + 8388608;            // 8,388,608 bf16
    unsigned short* Vb = Kb + 8388608;            // 8,388,608 bf16, [bh][d][n]
    // total workspace: 73,400,320 bytes

    k_cvt_x<<<4096, 256, 0, stream>>>(x, xb);
    k_tr_w<<<dim3(48, 16), 256, 0, stream>>>(W, Wt);
    k_qkv<<<dim3(24, 64), 256, 0, stream>>>(xb, Wt, b, Qb, Kb, Vb);
    k_attn<<<dim3(16, 64), 256, 0, stream>>>(Qb, Kb, Vb, out);
}